// Round 1
// baseline (111.443 us; speedup 1.0000x reference)
//
#include <hip/hip_runtime.h>
#include <math.h>

// HyperbolicDistanceHead: out[r][c] = -(2/sqrt(c)) * atanh(clip(sqrt(c)*sqrt(m2+1e-15), 0, 1-1e-5))
// B=128 rows (x), C=4096 cols (prototypes), D=1024, c=0.5.
// Design: lane = column; p staged in XOR-swizzled LDS (double-buffered, reg-staged);
// x rows read wave-uniformly (-> s_load); p2 fused into dot loop; x2 reduced in epilogue.

#define DDIM 1024
#define CDIM 4096
#define BDIM 128

__global__ __launch_bounds__(128) void hyper_dist_kernel(
    const float* __restrict__ x, const float* __restrict__ p, float* __restrict__ out) {
  __shared__ __align__(16) float ps[2][64][32];

  const int tid  = threadIdx.x;
  const int lane = tid & 63;
  const int w    = __builtin_amdgcn_readfirstlane(tid >> 6);  // wave id 0..1 (force uniform)
  const int colbase = blockIdx.x * 64;                        // 64 colgroups
  const int rowb    = blockIdx.y * 16 + w * 8;                // 8 rowgroups, 8 rows per wave

  // ---- staging indices: p tile is 64 p-rows x 32 k -> 512 float4, 128 threads x 4 reps
  int   prow[4], swz[4];
  const float* gp[4];
  #pragma unroll
  for (int r = 0; r < 4; ++r) {
    const int idx = tid + 128 * r;
    prow[r] = idx >> 3;                 // 0..63
    const int kqf = (idx & 7) << 2;     // 0,4,...,28 (float offset)
    swz[r] = kqf ^ ((prow[r] & 7) << 2);
    gp[r]  = p + (size_t)(colbase + prow[r]) * DDIM + kqf;
  }

  float acc[8] = {0.f, 0.f, 0.f, 0.f, 0.f, 0.f, 0.f, 0.f};
  float accp2 = 0.f;

  // ---- prologue: stage chunk 0 into buf 0
  {
    float4 rv[4];
    #pragma unroll
    for (int r = 0; r < 4; ++r) rv[r] = *(const float4*)(gp[r]);
    #pragma unroll
    for (int r = 0; r < 4; ++r) *(float4*)&ps[0][prow[r]][swz[r]] = rv[r];
  }
  __syncthreads();

  // ---- main K loop: 32 chunks of BK=32, double-buffered, one barrier per chunk
  for (int ch = 0; ch < 32; ++ch) {
    const int buf = ch & 1;
    const int k0  = ch * 32;

    float4 rv[4];
    if (ch < 31) {
      #pragma unroll
      for (int r = 0; r < 4; ++r) rv[r] = *(const float4*)(gp[r] + k0 + 32);
    }

    #pragma unroll
    for (int k4 = 0; k4 < 8; ++k4) {
      const float4 pv = *(const float4*)&ps[buf][lane][(k4 << 2) ^ ((lane & 7) << 2)];
      accp2 = fmaf(pv.x, pv.x, accp2);
      accp2 = fmaf(pv.y, pv.y, accp2);
      accp2 = fmaf(pv.z, pv.z, accp2);
      accp2 = fmaf(pv.w, pv.w, accp2);
      #pragma unroll
      for (int i = 0; i < 8; ++i) {
        // wave-uniform address -> scalar loads (s_load_dwordx4)
        const float4 xv = *(const float4*)(x + (size_t)(rowb + i) * DDIM + k0 + (k4 << 2));
        acc[i] = fmaf(xv.x, pv.x, acc[i]);
        acc[i] = fmaf(xv.y, pv.y, acc[i]);
        acc[i] = fmaf(xv.z, pv.z, acc[i]);
        acc[i] = fmaf(xv.w, pv.w, acc[i]);
      }
    }

    if (ch < 31) {
      #pragma unroll
      for (int r = 0; r < 4; ++r) *(float4*)&ps[buf ^ 1][prow[r]][swz[r]] = rv[r];
    }
    __syncthreads();
  }

  // ---- x2 per row (coalesced re-read of x, L2-resident; butterfly reduce)
  float x2v[8];
  #pragma unroll
  for (int i = 0; i < 8; ++i) {
    const float* xr = x + (size_t)(rowb + i) * DDIM;
    float s = 0.f;
    #pragma unroll
    for (int q = 0; q < 4; ++q) {
      const float4 v = *(const float4*)(xr + q * 256 + lane * 4);
      s = fmaf(v.x, v.x, s);
      s = fmaf(v.y, v.y, s);
      s = fmaf(v.z, v.z, s);
      s = fmaf(v.w, v.w, s);
    }
    #pragma unroll
    for (int off = 32; off > 0; off >>= 1) s += __shfl_xor(s, off, 64);
    x2v[i] = s;
  }

  // ---- epilogue: closed-form Poincare distance, c = 0.5
  const float p2 = accp2;  // per-lane = per-column
  #pragma unroll
  for (int i = 0; i < 8; ++i) {
    const float dot = acc[i];          // <x,p>; mdot = -dot
    const float x2  = x2v[i];
    const float A   = 1.0f - dot + 0.5f * p2;        // 1 + 2c*mdot + c*p2
    const float Bc  = 1.0f - 0.5f * x2;              // 1 - c*x2
    const float den = 1.0f - dot + 0.25f * x2 * p2;  // 1 + 2c*mdot + c^2*x2*p2
    float num2 = A * A * x2 - 2.0f * A * Bc * dot + Bc * Bc * p2;
    float m2   = fmaxf(num2, 0.0f) / fmaxf(den * den, 1e-15f);
    float arg  = fminf(0.7071067811865476f * sqrtf(m2 + 1e-15f), 0.99999f);
    // -(2/sqrt(c)) * atanh(arg) = -sqrt(2)*2*0.5*ln((1+z)/(1-z)) = -1.41421356*ln((1+z)/(1-z))
    const float val = -1.4142135623730951f * __logf((1.0f + arg) / (1.0f - arg));
    out[(size_t)(rowb + i) * CDIM + colbase + lane] = val;
  }
}

extern "C" void kernel_launch(void* const* d_in, const int* in_sizes, int n_in,
                              void* d_out, int out_size, void* d_ws, size_t ws_size,
                              hipStream_t stream) {
  const float* x = (const float*)d_in[0];   // [128,1024] fp32
  const float* p = (const float*)d_in[1];   // [4096,1024] fp32
  float* out = (float*)d_out;               // [128,4096] fp32
  dim3 grid(CDIM / 64, BDIM / 16, 1);       // (64, 8) -> 512 blocks; colgroup-major => XCD-local p tiles
  hyper_dist_kernel<<<grid, 128, 0, stream>>>(x, p, out);
}

// Round 2
// 51.941 us; speedup vs baseline: 2.1456x; 2.1456x over previous
//
#include <hip/hip_runtime.h>
#include <math.h>

// HyperbolicDistanceHead: out[r][c] = -(2/sqrt(c)) * atanh(clip(sqrt(c)*sqrt(m2+1e-15), 0, 1-1e-5))
// B=128, C=4096, D=1024, c=0.5. fp32, no MFMA (CDNA4 has no fp32 MFMA) -> VALU GEMM.
// Round 2: K-split x4 across waves (512-thr blocks, 8 waves = rowhalf x Kquarter),
// x staged in LDS (uniform broadcast reads), double-buffered p LDS, 16 waves/CU.

#define DDIM 1024
#define CDIM 4096

__global__ __launch_bounds__(512) void hyper_dist_kernel(
    const float* __restrict__ x, const float* __restrict__ p, float* __restrict__ out) {
  __shared__ __align__(16) float ps[2][4][64][32];   // 64 KB: [buf][Kquarter][col][k]
  __shared__ __align__(16) float xs[2][16][128];     // 16 KB: [buf][row][q*32+k]

  const int tid  = threadIdx.x;
  const int lane = tid & 63;
  const int w    = __builtin_amdgcn_readfirstlane(tid >> 6);  // wave 0..7
  const int q    = w >> 1;   // K-quarter 0..3 (K range q*256 .. +256)
  const int h    = w & 1;    // row half 0..1 (8 rows each)
  const int colbase = blockIdx.x * 64;
  const int rowbase = blockIdx.y * 16;

  // ---- p staging: rep r covers K-quarter r. t -> col=t>>3, k-offset=(t&7)*4
  const int pcol = tid >> 3;                  // 0..63
  const int pk   = (tid & 7) << 2;            // 0,4,...,28
  const int pswz = pk ^ ((pcol & 7) << 2);    // XOR swizzle (matches read side)
  const float* gpq[4];
  #pragma unroll
  for (int r = 0; r < 4; ++r)
    gpq[r] = p + (size_t)(colbase + pcol) * DDIM + r * 256 + pk;

  // ---- x staging: t -> row=t>>5, f4=t&31 -> quarter=f4>>3, k-offset=(f4&7)*4
  const int xrow = tid >> 5;                  // 0..15
  const int xf4  = tid & 31;
  const int xq   = xf4 >> 3;
  const int xk   = (xf4 & 7) << 2;
  const float* gx = x + (size_t)(rowbase + xrow) * DDIM + xq * 256 + xk;
  const int xdst = xq * 32 + xk;              // float offset within xs row

  float acc[8] = {0.f,0.f,0.f,0.f,0.f,0.f,0.f,0.f};
  float accp2 = 0.f;

  // ---- prologue: stage chunk 0 into buf 0
  {
    float4 pv[4];
    #pragma unroll
    for (int r = 0; r < 4; ++r) pv[r] = *(const float4*)(gpq[r]);
    float4 xv = *(const float4*)(gx);
    #pragma unroll
    for (int r = 0; r < 4; ++r) *(float4*)&ps[0][r][pcol][pswz] = pv[r];
    *(float4*)&xs[0][xrow][xdst] = xv;
  }
  __syncthreads();

  // ---- main loop: 8 chunks of 32 k per quarter, double-buffered, 1 barrier/chunk
  for (int ch = 0; ch < 8; ++ch) {
    const int buf = ch & 1;

    float4 pv[4]; float4 xv;
    if (ch < 7) {
      #pragma unroll
      for (int r = 0; r < 4; ++r) pv[r] = *(const float4*)(gpq[r] + (ch + 1) * 32);
      xv = *(const float4*)(gx + (ch + 1) * 32);
    }

    #pragma unroll
    for (int k4 = 0; k4 < 8; ++k4) {
      const float4 pf = *(const float4*)&ps[buf][q][lane][(k4 << 2) ^ ((lane & 7) << 2)];
      accp2 = fmaf(pf.x, pf.x, accp2);
      accp2 = fmaf(pf.y, pf.y, accp2);
      accp2 = fmaf(pf.z, pf.z, accp2);
      accp2 = fmaf(pf.w, pf.w, accp2);
      #pragma unroll
      for (int i = 0; i < 8; ++i) {
        // wave-uniform LDS address -> broadcast read, cheap
        const float4 xf = *(const float4*)&xs[buf][h * 8 + i][q * 32 + (k4 << 2)];
        acc[i] = fmaf(xf.x, pf.x, acc[i]);
        acc[i] = fmaf(xf.y, pf.y, acc[i]);
        acc[i] = fmaf(xf.z, pf.z, acc[i]);
        acc[i] = fmaf(xf.w, pf.w, acc[i]);
      }
    }

    if (ch < 7) {
      #pragma unroll
      for (int r = 0; r < 4; ++r) *(float4*)&ps[buf ^ 1][r][pcol][pswz] = pv[r];
      *(float4*)&xs[buf ^ 1][xrow][xdst] = xv;
    }
    __syncthreads();
  }

  // ---- combine K-quarter partials via LDS (reuse ps; lane stride 9 -> conflict-free)
  float* comb = (float*)ps;
  if (q > 0) {
    float* dst = comb + (size_t)(((q - 1) * 2 + h) * 64 + lane) * 9;
    #pragma unroll
    for (int j = 0; j < 8; ++j) dst[j] = acc[j];
    dst[8] = accp2;
  }
  __syncthreads();

  if (q == 0) {
    #pragma unroll
    for (int qq = 0; qq < 3; ++qq) {
      const float* s = comb + (size_t)((qq * 2 + h) * 64 + lane) * 9;
      #pragma unroll
      for (int j = 0; j < 8; ++j) acc[j] += s[j];
      accp2 += s[8];
    }

    // ---- x2 per row (coalesced global re-read, L2-resident; butterfly reduce)
    float x2v[8];
    #pragma unroll
    for (int i = 0; i < 8; ++i) {
      const float* xr = x + (size_t)(rowbase + h * 8 + i) * DDIM;
      float s = 0.f;
      #pragma unroll
      for (int q4 = 0; q4 < 4; ++q4) {
        const float4 v = *(const float4*)(xr + q4 * 256 + lane * 4);
        s = fmaf(v.x, v.x, s);
        s = fmaf(v.y, v.y, s);
        s = fmaf(v.z, v.z, s);
        s = fmaf(v.w, v.w, s);
      }
      #pragma unroll
      for (int off = 32; off > 0; off >>= 1) s += __shfl_xor(s, off, 64);
      x2v[i] = s;
    }

    // ---- epilogue: closed-form Poincare distance, c = 0.5
    const float p2 = accp2;  // per-lane = per-column
    #pragma unroll
    for (int i = 0; i < 8; ++i) {
      const float dot = acc[i];          // <x,p>; mdot = -dot
      const float x2  = x2v[i];
      const float A   = 1.0f - dot + 0.5f * p2;        // 1 + 2c*mdot + c*p2
      const float Bc  = 1.0f - 0.5f * x2;              // 1 - c*x2
      const float den = 1.0f - dot + 0.25f * x2 * p2;  // 1 + 2c*mdot + c^2*x2*p2
      float num2 = A * A * x2 - 2.0f * A * Bc * dot + Bc * Bc * p2;
      float m2   = fmaxf(num2, 0.0f) / fmaxf(den * den, 1e-15f);
      float arg  = fminf(0.7071067811865476f * sqrtf(m2 + 1e-15f), 0.99999f);
      const float val = -1.4142135623730951f * __logf((1.0f + arg) / (1.0f - arg));
      out[(size_t)(rowbase + h * 8 + i) * CDIM + colbase + lane] = val;
    }
  }
}

extern "C" void kernel_launch(void* const* d_in, const int* in_sizes, int n_in,
                              void* d_out, int out_size, void* d_ws, size_t ws_size,
                              hipStream_t stream) {
  const float* x = (const float*)d_in[0];   // [128,1024] fp32
  const float* p = (const float*)d_in[1];   // [4096,1024] fp32
  float* out = (float*)d_out;               // [128,4096] fp32
  dim3 grid(CDIM / 64, 128 / 16, 1);        // (64, 8) = 512 blocks of 512 thr
  // 64 % 8 XCDs == 0 -> all rowgroups of a colgroup land on the same XCD (p L2-local)
  hyper_dist_kernel<<<grid, 512, 0, stream>>>(x, p, out);
}

// Round 3
// 29.363 us; speedup vs baseline: 3.7954x; 1.7689x over previous
//
#include <hip/hip_runtime.h>
#include <hip/hip_bf16.h>
#include <math.h>

// HyperbolicDistanceHead via bf16 MFMA: out[r][c] = -(2/sqrt(c))*atanh(clip(...))
// B=128, C=4096, D=1024, c=0.5.
// dot(x_r, p_c) via mfma_f32_16x16x32_bf16 (inputs cvt'd fp32->bf16 in-register,
// both operands global->reg, no operand LDS). x2/p2 accumulated in fp32 from the
// pre-conversion loads. K-split x4 within block, combined via LDS.

#define DDIM 1024
#define CDIM 4096

using f32x4  = __attribute__((ext_vector_type(4))) float;
using bf16x8 = __attribute__((ext_vector_type(8))) short;

__device__ inline short toBf(float f) {
  __hip_bfloat16 h = __float2bfloat16(f);
  return *reinterpret_cast<short*>(&h);
}

__device__ inline bf16x8 cvtFrag(f32x4 a, f32x4 b) {
  bf16x8 r;
  r[0]=toBf(a[0]); r[1]=toBf(a[1]); r[2]=toBf(a[2]); r[3]=toBf(a[3]);
  r[4]=toBf(b[0]); r[5]=toBf(b[1]); r[6]=toBf(b[2]); r[7]=toBf(b[3]);
  return r;
}

__device__ inline float sq4(f32x4 v, float s) {
  s = fmaf(v[0],v[0],s); s = fmaf(v[1],v[1],s);
  s = fmaf(v[2],v[2],s); s = fmaf(v[3],v[3],s);
  return s;
}

__global__ __launch_bounds__(512, 4) void hyper_mfma(
    const float* __restrict__ x, const float* __restrict__ p, float* __restrict__ out) {
  __shared__ float accbuf[3][2][64][8];   // 12 KB: K-partials from kq=1..3
  __shared__ float x2s[4][32];            // per-kq x2 partials for block's 32 rows
  __shared__ float p2s[4][32];            // per-kq p2 partials for block's 32 cols
  __shared__ float x2t[32];
  __shared__ float p2t[32];

  const int tid  = threadIdx.x;
  const int lane = tid & 63;
  const int w    = __builtin_amdgcn_readfirstlane(tid >> 6);  // 0..7
  const int n    = w & 1;     // col-half (16 cols each)
  const int kq   = w >> 1;    // K-quarter 0..3 (256 k each)

  // XCD-chunk swizzle (512 % 8 == 0 -> bijective): 64 consecutive logical blocks/XCD
  const int bid = blockIdx.x;
  const int swz = ((bid & 7) << 6) | (bid >> 3);
  const int cg  = swz >> 2;   // 0..127 col-group (32 cols)
  const int mg  = swz & 3;    // 0..3 row-group (32 rows) — 4 mg's of a cg co-XCD
  const int rbase = mg * 32;
  const int cbase = cg * 32 + n * 16;
  const int r15 = lane & 15, g = lane >> 4;

  // A-frag: row = lane&15 (+16 for frag1), k = kq*256 + s*32 + g*8 + j
  const float* ax0 = x + (size_t)(rbase + r15) * DDIM + kq * 256 + g * 8;
  const float* ax1 = ax0 + (size_t)16 * DDIM;
  // B-frag: col = lane&15, same k pattern (p is [col][k] row-major = B^T)
  const float* bp  = p + (size_t)(cbase + r15) * DDIM + kq * 256 + g * 8;

  f32x4 acc0 = {0.f,0.f,0.f,0.f}, acc1 = {0.f,0.f,0.f,0.f};
  float x2p0 = 0.f, x2p1 = 0.f, p2p = 0.f;

  #pragma unroll
  for (int s = 0; s < 8; ++s) {
    const f32x4 A0a = *(const f32x4*)(ax0 + s*32);
    const f32x4 A0b = *(const f32x4*)(ax0 + s*32 + 4);
    const f32x4 A1a = *(const f32x4*)(ax1 + s*32);
    const f32x4 A1b = *(const f32x4*)(ax1 + s*32 + 4);
    const f32x4 Ba  = *(const f32x4*)(bp  + s*32);
    const f32x4 Bb  = *(const f32x4*)(bp  + s*32 + 4);
    x2p0 = sq4(A0a, x2p0); x2p0 = sq4(A0b, x2p0);
    x2p1 = sq4(A1a, x2p1); x2p1 = sq4(A1b, x2p1);
    p2p  = sq4(Ba,  p2p);  p2p  = sq4(Bb,  p2p);
    const bf16x8 af0 = cvtFrag(A0a, A0b);
    const bf16x8 af1 = cvtFrag(A1a, A1b);
    const bf16x8 bfr = cvtFrag(Ba,  Bb);
    acc0 = __builtin_amdgcn_mfma_f32_16x16x32_bf16(af0, bfr, acc0, 0, 0, 0);
    acc1 = __builtin_amdgcn_mfma_f32_16x16x32_bf16(af1, bfr, acc1, 0, 0, 0);
  }

  // fold the 4 lane-groups (lanes sharing lane&15) -> full sums over this wave's K-range
  x2p0 += __shfl_xor(x2p0, 16, 64); x2p0 += __shfl_xor(x2p0, 32, 64);
  x2p1 += __shfl_xor(x2p1, 16, 64); x2p1 += __shfl_xor(x2p1, 32, 64);
  p2p  += __shfl_xor(p2p,  16, 64); p2p  += __shfl_xor(p2p,  32, 64);

  if (lane < 16) {
    if (n == 0) { x2s[kq][r15] = x2p0; x2s[kq][16 + r15] = x2p1; }
    p2s[kq][n * 16 + r15] = p2p;
  }
  if (kq > 0) {
    float* dst = accbuf[kq - 1][n][lane];
    dst[0]=acc0[0]; dst[1]=acc0[1]; dst[2]=acc0[2]; dst[3]=acc0[3];
    dst[4]=acc1[0]; dst[5]=acc1[1]; dst[6]=acc1[2]; dst[7]=acc1[3];
  }
  __syncthreads();

  if (tid < 32) {
    x2t[tid] = x2s[0][tid] + x2s[1][tid] + x2s[2][tid] + x2s[3][tid];
  } else if (tid < 64) {
    const int c = tid - 32;
    p2t[c] = p2s[0][c] + p2s[1][c] + p2s[2][c] + p2s[3][c];
  }
  __syncthreads();

  if (kq == 0) {
    #pragma unroll
    for (int q = 0; q < 3; ++q) {
      const float* s = accbuf[q][n][lane];
      acc0[0]+=s[0]; acc0[1]+=s[1]; acc0[2]+=s[2]; acc0[3]+=s[3];
      acc1[0]+=s[4]; acc1[1]+=s[5]; acc1[2]+=s[6]; acc1[3]+=s[7];
    }
    const float p2 = p2t[n * 16 + r15];
    #pragma unroll
    for (int f = 0; f < 2; ++f) {
      const f32x4 a = f ? acc1 : acc0;
      #pragma unroll
      for (int i = 0; i < 4; ++i) {
        // C-frag: col = lane&15, row = (lane>>4)*4 + i  (verified m89 mapping)
        const int  rloc = f * 16 + g * 4 + i;
        const float dot = a[i];                           // <x,p>; mdot = -dot
        const float x2  = x2t[rloc];
        const float A   = 1.0f - dot + 0.5f  * p2;        // 1 + 2c*mdot + c*p2
        const float Bc  = 1.0f - 0.5f * x2;               // 1 - c*x2
        const float den = 1.0f - dot + 0.25f * x2 * p2;   // 1 + 2c*mdot + c^2*x2*p2
        float num2 = A * A * x2 - 2.0f * A * Bc * dot + Bc * Bc * p2;
        float m2   = fmaxf(num2, 0.0f) / fmaxf(den * den, 1e-15f);
        float arg  = fminf(0.7071067811865476f * sqrtf(m2 + 1e-15f), 0.99999f);
        out[(size_t)(rbase + rloc) * CDIM + cbase + r15] =
            -1.4142135623730951f * __logf((1.0f + arg) / (1.0f - arg));
      }
    }
  }
}

extern "C" void kernel_launch(void* const* d_in, const int* in_sizes, int n_in,
                              void* d_out, int out_size, void* d_ws, size_t ws_size,
                              hipStream_t stream) {
  const float* x = (const float*)d_in[0];   // [128,1024] fp32
  const float* p = (const float*)d_in[1];   // [4096,1024] fp32
  float* out = (float*)d_out;               // [128,4096] fp32
  hyper_mfma<<<dim3(512), dim3(512), 0, stream>>>(x, p, out);
}

// Round 4
// 19.599 us; speedup vs baseline: 5.6862x; 1.4982x over previous
//
#include <hip/hip_runtime.h>
#include <hip/hip_bf16.h>
#include <math.h>

// HyperbolicDistanceHead, two-pass:
//  K1: fp32 -> bf16 convert (once) + exact fp32 row sumsq for x and p.
//  K2: LDS-staged bf16 MFMA GEMM (global_load_lds w=16, XOR-swizzled both sides,
//      BK=256 x 4 chunks, 2-phase prefetch) + fused Poincare-distance epilogue.
// B=128, C=4096, D=1024, c=0.5.

#define DDIM 1024
#define CDIM 4096
#define BDIM 128

using f32x4  = __attribute__((ext_vector_type(4))) float;
using bf16x8 = __attribute__((ext_vector_type(8))) short;

#define GLOAD_LDS16(gp, lp) __builtin_amdgcn_global_load_lds(          \
    (const __attribute__((address_space(1))) void*)(gp),               \
    (__attribute__((address_space(3))) void*)(lp), 16, 0, 0)

__device__ inline short toBf(float f) {
  __hip_bfloat16 h = __float2bfloat16(f);
  return *reinterpret_cast<short*>(&h);
}

// ---------------- Kernel 1: convert + norms ----------------
// virtual rows 0..4223: 0..127 = x, 128..4223 = p. 4 rows/block, 256 thr.
__global__ __launch_bounds__(256) void cvt_norms(
    const float* __restrict__ x, const float* __restrict__ p,
    ushort* __restrict__ xb, ushort* __restrict__ pb,
    float* __restrict__ x2, float* __restrict__ p2) {
  __shared__ float part[4][4];  // [wave][row]
  const int tid  = threadIdx.x;
  const int lane = tid & 63;
  const int w    = tid >> 6;
  const int r0   = blockIdx.x * 4;

  float s[4];
  #pragma unroll
  for (int r = 0; r < 4; ++r) {
    const int row = r0 + r;
    const float* src = (row < BDIM) ? (x + (size_t)row * DDIM)
                                    : (p + (size_t)(row - BDIM) * DDIM);
    ushort* dst = (row < BDIM) ? (xb + (size_t)row * DDIM)
                               : (pb + (size_t)(row - BDIM) * DDIM);
    const f32x4 v = *(const f32x4*)(src + tid * 4);
    float a = v[0] * v[0];
    a = fmaf(v[1], v[1], a);
    a = fmaf(v[2], v[2], a);
    a = fmaf(v[3], v[3], a);
    s[r] = a;
    ushort4 o;
    o.x = (ushort)toBf(v[0]); o.y = (ushort)toBf(v[1]);
    o.z = (ushort)toBf(v[2]); o.w = (ushort)toBf(v[3]);
    *(ushort4*)(dst + tid * 4) = o;
  }
  #pragma unroll
  for (int r = 0; r < 4; ++r) {
    float a = s[r];
    #pragma unroll
    for (int off = 32; off > 0; off >>= 1) a += __shfl_xor(a, off, 64);
    if (lane == 0) part[w][r] = a;
  }
  __syncthreads();
  if (tid < 4) {
    const float tot = part[0][tid] + part[1][tid] + part[2][tid] + part[3][tid];
    const int row = r0 + tid;
    if (row < BDIM) x2[row] = tot; else p2[row - BDIM] = tot;
  }
}

// ---------------- Kernel 2: staged bf16 MFMA GEMM + epilogue ----------------
// Block: 32 rows x 32 cols, 8 waves = (n in {0,1} col-half, kq in 0..3 K-slice).
// K chunked: 4 chunks of 256; LDS [2 bufs][A 32x256 | B 32x256] bf16 = 64 KB.
__global__ __launch_bounds__(512, 4) void hyper_gemm(
    const ushort* __restrict__ xb, const ushort* __restrict__ pb,
    const float* __restrict__ x2a, const float* __restrict__ p2a,
    float* __restrict__ out) {
  __shared__ __align__(16) char smem[2][32768];   // [buf][A 16K | B 16K]

  const int tid  = threadIdx.x;
  const int lane = tid & 63;
  const int w    = __builtin_amdgcn_readfirstlane(tid >> 6);  // 0..7
  const int n    = w & 1;     // col-half (16 cols)
  const int kq   = w >> 1;    // K-slice within chunk (64 elems)

  // bijective XCD swizzle (512 % 8 == 0): each XCD owns 16 contiguous colgroups
  const int bid = blockIdx.x;
  const int swz = ((bid & 7) << 6) | (bid >> 3);
  const int cg  = swz >> 2;   // 0..127
  const int mg  = swz & 3;    // 0..3
  const int rbase = mg * 32;
  const int cbase = cg * 32;
  const int r15 = lane & 15, g = lane >> 4;

  const int lhalf  = lane >> 5;        // staging: 2 LDS rows (512B) per 1KB slot
  const int lsrc16 = (lane & 31) << 4;
  const int swr    = (r15 & 7) << 4;   // read-side XOR

  f32x4 acc0 = {0.f,0.f,0.f,0.f}, acc1 = {0.f,0.f,0.f,0.f};

  // stage chunk c into buf: 32 slots of 1KB; slot s = w*4+i; rows = 2/slot.
  // LDS linear dest; SOURCE pre-swizzled so LDS[row*512 + j] = G[j ^ ((row&7)<<4)].
  auto stage = [&](int buf, int c) {
    #pragma unroll
    for (int i = 0; i < 4; ++i) {
      const int s    = w * 4 + i;
      const int rloc = ((s & 15) << 1) | lhalf;               // 0..31
      const int srcb = lsrc16 ^ ((rloc & 7) << 4);
      char* lp = &smem[buf][s * 1024];
      if (s < 16) {  // A tile: x rows (wave-uniform branch: w<4)
        const char* gp = (const char*)xb + (size_t)(rbase + rloc) * 2048 + c * 512 + srcb;
        GLOAD_LDS16(gp, lp);
      } else {       // B tile: p rows
        const char* gp = (const char*)pb + (size_t)(cbase + rloc) * 2048 + c * 512 + srcb;
        GLOAD_LDS16(gp, lp);
      }
    }
  };

  stage(0, 0);
  __syncthreads();   // drains vmcnt -> buf0 ready

  #pragma unroll
  for (int c = 0; c < 4; ++c) {
    const int buf = c & 1;
    if (c < 3) stage(buf ^ 1, c + 1);   // prefetch: latency hides under compute
    #pragma unroll
    for (int ks = 0; ks < 2; ++ks) {
      const int inrow = kq * 128 + ks * 64 + (g << 4);        // byte offset in 512B row
      const int off   = inrow ^ swr;
      const bf16x8 a0 = *(const bf16x8*)&smem[buf][(size_t)r15 * 512 + off];
      const bf16x8 a1 = *(const bf16x8*)&smem[buf][(size_t)(16 + r15) * 512 + off];
      const bf16x8 bb = *(const bf16x8*)&smem[buf][16384 + (size_t)(n * 16 + r15) * 512 + off];
      acc0 = __builtin_amdgcn_mfma_f32_16x16x32_bf16(a0, bb, acc0, 0, 0, 0);
      acc1 = __builtin_amdgcn_mfma_f32_16x16x32_bf16(a1, bb, acc1, 0, 0, 0);
    }
    __syncthreads();   // drains prefetch loads + releases buf for next overwrite
  }

  // ---- combine K-slice partials (reuse smem[0]; stride 9 words -> bank-spread)
  float* accbuf = (float*)&smem[0][0];
  if (kq > 0) {
    float* dst = accbuf + (size_t)(((kq - 1) * 2 + n) * 64 + lane) * 9;
    dst[0]=acc0[0]; dst[1]=acc0[1]; dst[2]=acc0[2]; dst[3]=acc0[3];
    dst[4]=acc1[0]; dst[5]=acc1[1]; dst[6]=acc1[2]; dst[7]=acc1[3];
  }
  __syncthreads();

  if (kq == 0) {
    #pragma unroll
    for (int q = 0; q < 3; ++q) {
      const float* sp = accbuf + (size_t)((q * 2 + n) * 64 + lane) * 9;
      acc0[0]+=sp[0]; acc0[1]+=sp[1]; acc0[2]+=sp[2]; acc0[3]+=sp[3];
      acc1[0]+=sp[4]; acc1[1]+=sp[5]; acc1[2]+=sp[6]; acc1[3]+=sp[7];
    }
    const float p2 = p2a[cbase + n * 16 + r15];
    #pragma unroll
    for (int f = 0; f < 2; ++f) {
      const f32x4 a = f ? acc1 : acc0;
      #pragma unroll
      for (int i = 0; i < 4; ++i) {
        // C-frag: col = lane&15, row = (lane>>4)*4 + i (verified m89 mapping)
        const int  rloc = f * 16 + g * 4 + i;
        const float dot = a[i];                           // <x,p>; mdot = -dot
        const float x2  = x2a[rbase + rloc];
        const float A   = 1.0f - dot + 0.5f  * p2;        // 1 + 2c*mdot + c*p2
        const float Bc  = 1.0f - 0.5f * x2;               // 1 - c*x2
        const float den = 1.0f - dot + 0.25f * x2 * p2;   // 1 + 2c*mdot + c^2*x2*p2
        float num2 = A * A * x2 - 2.0f * A * Bc * dot + Bc * Bc * p2;
        float m2   = fmaxf(num2, 0.0f) / fmaxf(den * den, 1e-15f);
        float arg  = fminf(0.7071067811865476f * sqrtf(m2 + 1e-15f), 0.99999f);
        out[(size_t)(rbase + rloc) * CDIM + cbase + n * 16 + r15] =
            -1.4142135623730951f * __logf((1.0f + arg) / (1.0f - arg));
      }
    }
  }
}

// ---------------- Fallback (round-3 kernel, used if ws too small) ----------------
__device__ inline bf16x8 cvtFrag(f32x4 a, f32x4 b) {
  bf16x8 r;
  r[0]=toBf(a[0]); r[1]=toBf(a[1]); r[2]=toBf(a[2]); r[3]=toBf(a[3]);
  r[4]=toBf(b[0]); r[5]=toBf(b[1]); r[6]=toBf(b[2]); r[7]=toBf(b[3]);
  return r;
}
__device__ inline float sq4(f32x4 v, float s) {
  s = fmaf(v[0],v[0],s); s = fmaf(v[1],v[1],s);
  s = fmaf(v[2],v[2],s); s = fmaf(v[3],v[3],s);
  return s;
}
__global__ __launch_bounds__(512, 4) void hyper_mfma(
    const float* __restrict__ x, const float* __restrict__ p, float* __restrict__ out) {
  __shared__ float accbuf[3][2][64][8];
  __shared__ float x2s[4][32];
  __shared__ float p2s[4][32];
  __shared__ float x2t[32];
  __shared__ float p2t[32];
  const int tid  = threadIdx.x;
  const int lane = tid & 63;
  const int w    = __builtin_amdgcn_readfirstlane(tid >> 6);
  const int n    = w & 1;
  const int kq   = w >> 1;
  const int bid = blockIdx.x;
  const int swz = ((bid & 7) << 6) | (bid >> 3);
  const int cg  = swz >> 2;
  const int mg  = swz & 3;
  const int rbase = mg * 32;
  const int cbase = cg * 32 + n * 16;
  const int r15 = lane & 15, g = lane >> 4;
  const float* ax0 = x + (size_t)(rbase + r15) * DDIM + kq * 256 + g * 8;
  const float* ax1 = ax0 + (size_t)16 * DDIM;
  const float* bp  = p + (size_t)(cbase + r15) * DDIM + kq * 256 + g * 8;
  f32x4 acc0 = {0.f,0.f,0.f,0.f}, acc1 = {0.f,0.f,0.f,0.f};
  float x2p0 = 0.f, x2p1 = 0.f, p2p = 0.f;
  #pragma unroll
  for (int s = 0; s < 8; ++s) {
    const f32x4 A0a = *(const f32x4*)(ax0 + s*32);
    const f32x4 A0b = *(const f32x4*)(ax0 + s*32 + 4);
    const f32x4 A1a = *(const f32x4*)(ax1 + s*32);
    const f32x4 A1b = *(const f32x4*)(ax1 + s*32 + 4);
    const f32x4 Ba  = *(const f32x4*)(bp  + s*32);
    const f32x4 Bb  = *(const f32x4*)(bp  + s*32 + 4);
    x2p0 = sq4(A0a, x2p0); x2p0 = sq4(A0b, x2p0);
    x2p1 = sq4(A1a, x2p1); x2p1 = sq4(A1b, x2p1);
    p2p  = sq4(Ba,  p2p);  p2p  = sq4(Bb,  p2p);
    const bf16x8 af0 = cvtFrag(A0a, A0b);
    const bf16x8 af1 = cvtFrag(A1a, A1b);
    const bf16x8 bfr = cvtFrag(Ba,  Bb);
    acc0 = __builtin_amdgcn_mfma_f32_16x16x32_bf16(af0, bfr, acc0, 0, 0, 0);
    acc1 = __builtin_amdgcn_mfma_f32_16x16x32_bf16(af1, bfr, acc1, 0, 0, 0);
  }
  x2p0 += __shfl_xor(x2p0, 16, 64); x2p0 += __shfl_xor(x2p0, 32, 64);
  x2p1 += __shfl_xor(x2p1, 16, 64); x2p1 += __shfl_xor(x2p1, 32, 64);
  p2p  += __shfl_xor(p2p,  16, 64); p2p  += __shfl_xor(p2p,  32, 64);
  if (lane < 16) {
    if (n == 0) { x2s[kq][r15] = x2p0; x2s[kq][16 + r15] = x2p1; }
    p2s[kq][n * 16 + r15] = p2p;
  }
  if (kq > 0) {
    float* dst = accbuf[kq - 1][n][lane];
    dst[0]=acc0[0]; dst[1]=acc0[1]; dst[2]=acc0[2]; dst[3]=acc0[3];
    dst[4]=acc1[0]; dst[5]=acc1[1]; dst[6]=acc1[2]; dst[7]=acc1[3];
  }
  __syncthreads();
  if (tid < 32) {
    x2t[tid] = x2s[0][tid] + x2s[1][tid] + x2s[2][tid] + x2s[3][tid];
  } else if (tid < 64) {
    const int c = tid - 32;
    p2t[c] = p2s[0][c] + p2s[1][c] + p2s[2][c] + p2s[3][c];
  }
  __syncthreads();
  if (kq == 0) {
    #pragma unroll
    for (int q = 0; q < 3; ++q) {
      const float* s = accbuf[q][n][lane];
      acc0[0]+=s[0]; acc0[1]+=s[1]; acc0[2]+=s[2]; acc0[3]+=s[3];
      acc1[0]+=s[4]; acc1[1]+=s[5]; acc1[2]+=s[6]; acc1[3]+=s[7];
    }
    const float p2 = p2t[n * 16 + r15];
    #pragma unroll
    for (int f = 0; f < 2; ++f) {
      const f32x4 a = f ? acc1 : acc0;
      #pragma unroll
      for (int i = 0; i < 4; ++i) {
        const int  rloc = f * 16 + g * 4 + i;
        const float dot = a[i];
        const float x2  = x2t[rloc];
        const float A   = 1.0f - dot + 0.5f  * p2;
        const float Bc  = 1.0f - 0.5f * x2;
        const float den = 1.0f - dot + 0.25f * x2 * p2;
        float num2 = A * A * x2 - 2.0f * A * Bc * dot + Bc * Bc * p2;
        float m2   = fmaxf(num2, 0.0f) / fmaxf(den * den, 1e-15f);
        float arg  = fminf(0.7071067811865476f * sqrtf(m2 + 1e-15f), 0.99999f);
        out[(size_t)(rbase + rloc) * CDIM + cbase + r15] =
            -1.4142135623730951f * __logf((1.0f + arg) / (1.0f - arg));
      }
    }
  }
}

extern "C" void kernel_launch(void* const* d_in, const int* in_sizes, int n_in,
                              void* d_out, int out_size, void* d_ws, size_t ws_size,
                              hipStream_t stream) {
  const float* x = (const float*)d_in[0];   // [128,1024] fp32
  const float* p = (const float*)d_in[1];   // [4096,1024] fp32
  float* out = (float*)d_out;               // [128,4096] fp32

  // ws layout: pb[4096*1024]bf16 | xb[128*1024]bf16 | x2[128]f32 | p2[4096]f32
  const size_t PB = (size_t)CDIM * DDIM * 2;          // 8388608
  const size_t XB = (size_t)BDIM * DDIM * 2;          // 262144
  const size_t NEED = PB + XB + BDIM * 4 + CDIM * 4;  // 8667648

  if (ws_size >= NEED) {
    ushort* pb = (ushort*)d_ws;
    ushort* xb = (ushort*)((char*)d_ws + PB);
    float*  x2 = (float*)((char*)d_ws + PB + XB);
    float*  p2 = (float*)((char*)d_ws + PB + XB + BDIM * 4);
    cvt_norms<<<dim3((BDIM + CDIM) / 4), dim3(256), 0, stream>>>(x, p, xb, pb, x2, p2);
    hyper_gemm<<<dim3(512), dim3(512), 0, stream>>>(xb, pb, x2, p2, out);
  } else {
    hyper_mfma<<<dim3(512), dim3(512), 0, stream>>>(x, p, out);
  }
}

// Round 5
// 19.146 us; speedup vs baseline: 5.8207x; 1.0237x over previous
//
#include <hip/hip_runtime.h>
#include <hip/hip_bf16.h>
#include <math.h>

// HyperbolicDistanceHead, fused: out[r][c] = -(2/sqrt(c))*atanh(clip(...)), c=0.5
// B=128, C=4096, D=1024.
//  K1: x fp32 -> xb bf16 (row-major) + exact fp32 x2[128].  (0.75 MB traffic)
//  K2: grid 256 x 512thr; block = 128 rows x 16 p-cols, full K per wave.
//      p read ONCE from HBM as fp32, cvt'd in-register during staging (p2 fused);
//      x staged bf16 via global_load_lds w=16 (source-side XOR swizzle, linear LDS
//      dest, swizzled ds_read -> conflict-free); double-buffered BK=128, T14 split.

#define DDIM 1024
#define CDIM 4096
#define BDIM 128

using f32x4  = __attribute__((ext_vector_type(4))) float;
using bf16x8 = __attribute__((ext_vector_type(8))) short;

#define GLOAD_LDS16(gp, lp) __builtin_amdgcn_global_load_lds(          \
    (const __attribute__((address_space(1))) void*)(gp),               \
    (__attribute__((address_space(3))) void*)(lp), 16, 0, 0)

__device__ inline ushort toBfU(float f) {
  __hip_bfloat16 h = __float2bfloat16(f);
  return *reinterpret_cast<ushort*>(&h);
}

__device__ inline float sq4(f32x4 v, float s) {
  s = fmaf(v[0], v[0], s); s = fmaf(v[1], v[1], s);
  s = fmaf(v[2], v[2], s); s = fmaf(v[3], v[3], s);
  return s;
}

// ---------------- K1: x -> bf16 + exact row sumsq ----------------
__global__ __launch_bounds__(256) void x_prep(
    const float* __restrict__ x, ushort* __restrict__ xb, float* __restrict__ x2) {
  __shared__ float part[4];
  const int tid = threadIdx.x, lane = tid & 63, w = tid >> 6;
  const int row = blockIdx.x;
  const f32x4 v = *(const f32x4*)(x + (size_t)row * DDIM + tid * 4);
  float a = v[0] * v[0];
  a = fmaf(v[1], v[1], a); a = fmaf(v[2], v[2], a); a = fmaf(v[3], v[3], a);
  ushort4 o = { toBfU(v[0]), toBfU(v[1]), toBfU(v[2]), toBfU(v[3]) };
  *(ushort4*)(xb + (size_t)row * DDIM + tid * 4) = o;
  #pragma unroll
  for (int off = 32; off > 0; off >>= 1) a += __shfl_xor(a, off, 64);
  if (lane == 0) part[w] = a;
  __syncthreads();
  if (tid == 0) x2[row] = part[0] + part[1] + part[2] + part[3];
}

// ---------------- K2: fused GEMM + p-convert + epilogue ----------------
// Block: 128 rows x 16 cols; 8 waves, wave w = rows 16w..16w+15, full K.
// LDS: xs[2][128 rows][256 B] = 64 KB, ps[2][16 cols][256 B] = 8 KB.
__global__ __launch_bounds__(512) void hyper_fused(
    const ushort* __restrict__ xb, const float* __restrict__ p,
    const float* __restrict__ x2a, float* __restrict__ out) {
  __shared__ __align__(16) char xs[2][32768];
  __shared__ __align__(16) char ps[2][4096];
  __shared__ float p2t[16];

  const int tid  = threadIdx.x;
  const int lane = tid & 63;
  const int w    = __builtin_amdgcn_readfirstlane(tid >> 6);  // 0..7
  const int r15  = lane & 15, g = lane >> 4;

  // bijective XCD chunk swizzle (256 % 8 == 0): 32 contiguous colgroups per XCD
  const int bid = blockIdx.x;
  const int swz = ((bid & 7) << 5) | (bid >> 3);
  const int cbase = swz * 16;

  // p staging: thread -> col = tid>>5 (0..15), elems (tid&31)*4 within chunk
  const int prow = tid >> 5;
  const int pj   = tid & 31;
  const float* pg = p + (size_t)(cbase + prow) * DDIM + pj * 4;
  const int pdst = prow * 256 + ((pj << 3) ^ ((prow & 7) << 4));  // 8B-aligned

  f32x4 acc = {0.f, 0.f, 0.f, 0.f};
  float p2p = 0.f;

  // x staging: 4 segs/wave; seg covers 4 rows x 256 B; lane l -> LDS seg*1024 + l*16
  // LDS dest LINEAR; global source per-lane XOR-swizzled (rule 21)
  auto stageX = [&](int buf, int c) {
    #pragma unroll
    for (int i = 0; i < 4; ++i) {
      const int seg = w * 4 + i;
      const int row = seg * 4 + (lane >> 4);
      const int cb  = (lane & 15) << 4;
      const char* gp = (const char*)xb + (size_t)row * 2048 + c * 256 + (cb ^ ((row & 7) << 4));
      char* lp = &xs[buf][seg * 1024 + lane * 16];
      GLOAD_LDS16(gp, lp);
    }
  };

  // prologue: stage chunk 0 into buf 0
  {
    const f32x4 pv = *(const f32x4*)(pg);
    stageX(0, 0);
    p2p = sq4(pv, p2p);
    ushort4 o = { toBfU(pv[0]), toBfU(pv[1]), toBfU(pv[2]), toBfU(pv[3]) };
    *(ushort4*)&ps[0][pdst] = o;
  }
  __syncthreads();

  // main loop: 8 chunks of BK=128; prefetch-issue early, p-write after compute
  #pragma unroll
  for (int c = 0; c < 8; ++c) {
    const int buf = c & 1;
    f32x4 pv;
    if (c < 7) {
      pv = *(const f32x4*)(pg + (c + 1) * 128);   // p fp32 -> reg (latency under MFMA)
      stageX(buf ^ 1, c + 1);                     // x bf16 -> LDS DMA
    }

    const int arow = (w << 4) + r15;              // arow&7 == r15&7
    #pragma unroll
    for (int ks = 0; ks < 4; ++ks) {
      const int off = ((ks << 6) + (g << 4)) ^ ((r15 & 7) << 4);
      const bf16x8 a = *(const bf16x8*)&xs[buf][arow * 256 + off];
      const bf16x8 b = *(const bf16x8*)&ps[buf][r15 * 256 + off];
      acc = __builtin_amdgcn_mfma_f32_16x16x32_bf16(a, b, acc, 0, 0, 0);
    }

    if (c < 7) {
      p2p = sq4(pv, p2p);
      ushort4 o = { toBfU(pv[0]), toBfU(pv[1]), toBfU(pv[2]), toBfU(pv[3]) };
      *(ushort4*)&ps[buf ^ 1][pdst] = o;
    }
    __syncthreads();
  }

  // ---- p2 reduce: 32 threads per col (lanes 0-31 = col 2w, 32-63 = col 2w+1)
  #pragma unroll
  for (int off = 16; off > 0; off >>= 1) p2p += __shfl_xor(p2p, off, 64);
  if ((lane & 31) == 0) p2t[(w << 1) | (lane >> 5)] = p2p;
  __syncthreads();

  // ---- epilogue: closed-form Poincare distance, c = 0.5
  const float p2 = p2t[r15];
  #pragma unroll
  for (int i = 0; i < 4; ++i) {
    // C-frag: col = lane&15, row = (lane>>4)*4 + i (verified m89 mapping)
    const int  row = (w << 4) + (g << 2) + i;
    const float dot = acc[i];                          // <x,p>; mdot = -dot
    const float x2  = x2a[row];
    const float A   = 1.0f - dot + 0.5f  * p2;         // 1 + 2c*mdot + c*p2
    const float Bc  = 1.0f - 0.5f * x2;                // 1 - c*x2
    const float den = 1.0f - dot + 0.25f * x2 * p2;    // 1 + 2c*mdot + c^2*x2*p2
    float num2 = A * A * x2 - 2.0f * A * Bc * dot + Bc * Bc * p2;
    float m2   = fmaxf(num2, 0.0f) / fmaxf(den * den, 1e-15f);
    float arg  = fminf(0.7071067811865476f * sqrtf(m2 + 1e-15f), 0.99999f);
    out[(size_t)row * CDIM + cbase + r15] =
        -1.4142135623730951f * __logf((1.0f + arg) / (1.0f - arg));
  }
}

extern "C" void kernel_launch(void* const* d_in, const int* in_sizes, int n_in,
                              void* d_out, int out_size, void* d_ws, size_t ws_size,
                              hipStream_t stream) {
  const float* x = (const float*)d_in[0];   // [128,1024] fp32
  const float* p = (const float*)d_in[1];   // [4096,1024] fp32
  float* out = (float*)d_out;               // [128,4096] fp32

  // ws: xb[128*1024] bf16 | x2[128] f32   (needs 262656 B; harness ws >= 8.6 MB)
  ushort* xb = (ushort*)d_ws;
  float*  x2 = (float*)((char*)d_ws + (size_t)BDIM * DDIM * 2);

  x_prep<<<dim3(BDIM), dim3(256), 0, stream>>>(x, xb, x2);
  hyper_fused<<<dim3(256), dim3(512), 0, stream>>>(xb, p, x2, out);
}